// Round 8
// baseline (730.781 us; speedup 1.0000x reference)
//
#include <hip/hip_runtime.h>
#include <hip/hip_bf16.h>
#include <stdint.h>

#define DD 128

typedef _Float16 f16;
typedef f16 f16x2 __attribute__((ext_vector_type(2)));
typedef f16 f16x4 __attribute__((ext_vector_type(4)));
typedef f16 f16x8 __attribute__((ext_vector_type(8)));
typedef float f32x4 __attribute__((ext_vector_type(4)));

// pack col(17b) | sign-less f16 weight (15b, w>0) in one u32
__device__ __forceinline__ unsigned packcw(int c, float w) {
  f16 h = (f16)w;
  unsigned short us;
  __builtin_memcpy(&us, &h, 2);
  return ((unsigned)us << 17) | (unsigned)c;
}
__device__ __forceinline__ float unpackw(unsigned p) {
  unsigned short us = (unsigned short)(p >> 17);
  f16 h;
  __builtin_memcpy(&h, &us, 2);
  return (float)h;
}
__device__ __forceinline__ int unpackc(unsigned p) { return (int)(p & 0x1FFFFu); }

// ---------------- graph-norm precompute ----------------
__global__ __launch_bounds__(256) void k_zero(unsigned* degE, int n) {
  int i = blockIdx.x * 256 + threadIdx.x;
  if (i < n) degE[i] = 0u;
}

// degree count + per-edge rank (old count value) in one atomic.
__global__ __launch_bounds__(256) void k_deg_count(const int* __restrict__ row,
                                                   unsigned* degE,
                                                   unsigned short* __restrict__ rank,
                                                   int E) {
  int e = blockIdx.x * 256 + threadIdx.x;
  if (e < E) rank[e] = (unsigned short)atomicAdd(&degE[row[e]], 1u);
}

// ---------------- exclusive scan of degE -> rowptr (+ fused dinv) --------------
__global__ __launch_bounds__(256) void k_scan1(const unsigned* __restrict__ degE,
                                               unsigned* __restrict__ rowptr,
                                               unsigned* __restrict__ bsum,
                                               float* __restrict__ dinv, int n) {
  __shared__ unsigned sh[256];
  int tid = threadIdx.x;
  int base = blockIdx.x * 1024 + tid * 4;
  unsigned v0 = (base + 0 < n) ? degE[base + 0] : 0u;
  unsigned v1 = (base + 1 < n) ? degE[base + 1] : 0u;
  unsigned v2 = (base + 2 < n) ? degE[base + 2] : 0u;
  unsigned v3 = (base + 3 < n) ? degE[base + 3] : 0u;
  if (base + 0 < n) dinv[base + 0] = rsqrtf((float)(v0 + 1u));
  if (base + 1 < n) dinv[base + 1] = rsqrtf((float)(v1 + 1u));
  if (base + 2 < n) dinv[base + 2] = rsqrtf((float)(v2 + 1u));
  if (base + 3 < n) dinv[base + 3] = rsqrtf((float)(v3 + 1u));
  unsigned p1 = v0, p2 = p1 + v1, p3 = p2 + v2, tot = p3 + v3;
  sh[tid] = tot;
  __syncthreads();
  for (int off = 1; off < 256; off <<= 1) {
    unsigned t = (tid >= off) ? sh[tid - off] : 0u;
    __syncthreads();
    sh[tid] += t;
    __syncthreads();
  }
  unsigned excl = sh[tid] - tot;
  if (base + 0 < n) rowptr[base + 0] = excl;
  if (base + 1 < n) rowptr[base + 1] = excl + p1;
  if (base + 2 < n) rowptr[base + 2] = excl + p2;
  if (base + 3 < n) rowptr[base + 3] = excl + p3;
  if (tid == 255) bsum[blockIdx.x] = sh[255];
}

__global__ __launch_bounds__(256) void k_scan2(const unsigned* __restrict__ bsum,
                                               unsigned* __restrict__ boff, int nb) {
  __shared__ unsigned sh[256];
  int tid = threadIdx.x;
  unsigned x = (tid < nb) ? bsum[tid] : 0u;
  sh[tid] = x;
  __syncthreads();
  for (int off = 1; off < 256; off <<= 1) {
    unsigned t = (tid >= off) ? sh[tid - off] : 0u;
    __syncthreads();
    sh[tid] += t;
    __syncthreads();
  }
  if (tid < nb) boff[tid] = sh[tid] - x;
}

__global__ __launch_bounds__(256) void k_scan3(unsigned* rowptr,
                                               const unsigned* __restrict__ boff, int n) {
  int i = blockIdx.x * 256 + threadIdx.x;
  if (i < n) rowptr[i] += boff[i >> 10];
}

// ---------------- fill CSR, atomic-free (pos = rowptr[r] + rank[e]) ------------
__global__ __launch_bounds__(256) void k_fill(const int* __restrict__ row,
                                              const int* __restrict__ col,
                                              const unsigned short* __restrict__ rank,
                                              const float* __restrict__ dinv,
                                              const unsigned* __restrict__ rowptr,
                                              unsigned* __restrict__ ep,
                                              int E, int N) {
  const int xcd = blockIdx.x & 7;
  const int blk = blockIdx.x >> 3;  // 0..255
  const int r0 = (int)((size_t)N * xcd / 8);
  const int r1 = (int)((size_t)N * (xcd + 1) / 8);
  const int e0 = (int)((size_t)E * blk / 256);
  const int e1 = (int)((size_t)E * (blk + 1) / 256);
  for (int e = e0 + (int)threadIdx.x; e < e1; e += 256) {
    int r = row[e];
    if (r >= r0 && r < r1) {
      int c = col[e];
      float w = dinv[r] * dinv[c];
      ep[rowptr[r] + (unsigned)rank[e]] = packcw(c, w);
    }
  }
}

// ---------------- x fp32 -> f16 (one-time) ----------------
__global__ __launch_bounds__(256) void k_xcast(const float* __restrict__ X,
                                               f16* __restrict__ Y, int nv8) {
  int i = blockIdx.x * 256 + threadIdx.x;
  if (i >= nv8) return;
  f32x4 a = ((const f32x4*)X)[i * 2];
  f32x4 b = ((const f32x4*)X)[i * 2 + 1];
  f16x8 o;
#pragma unroll
  for (int j = 0; j < 4; ++j) {
    o[j] = (f16)a[j];
    o[j + 4] = (f16)b[j];
  }
  ((f16x8*)Y)[i] = o;
}

// ---------------- all 3 W -> transposed f16 in one launch ----------------------
__global__ __launch_bounds__(256) void k_wt3(const float* __restrict__ W0,
                                             const float* __restrict__ W1,
                                             const float* __restrict__ W2,
                                             f16* __restrict__ T0,
                                             f16* __restrict__ T1,
                                             f16* __restrict__ T2) {
  int i = blockIdx.x * 256 + threadIdx.x;  // over 3*16384
  int m = i >> 14, j = i & 16383;
  const float* W = (m == 0) ? W0 : (m == 1) ? W1 : W2;
  f16* T = (m == 0) ? T0 : (m == 1) ? T1 : T2;
  int k = j >> 7, c = j & 127;
  T[c * 128 + k] = (f16)W[j];
}

// ---------------- GEMM: A_sl = H16[n,128] @ W[128,128], f16 MFMA ---------------
// Output in SLICED layout: A_sl[slice=col/16][row][col%16] (f16), so the agg
// kernel's per-slice working set (3.2 MB) fits one XCD's 4 MB L2.
__global__ __launch_bounds__(512, 4) void k_gemm_mfma(const f16* __restrict__ H,
                                                      const f16* __restrict__ Wt,
                                                      f16* __restrict__ O, int n) {
  __shared__ short WT[16384];  // 128 cols x 256 B, XOR-swizzled
  const int tx = threadIdx.x;
  const int w = tx >> 6, l = tx & 63;
  const int cl = l & 15, lg = l >> 4;
  const int rbase = blockIdx.x * 128 + w * 16;

  // stage W (2048 16B-units, 4 per thread)
#pragma unroll
  for (int t4 = 0; t4 < 4; ++t4) {
    int idx = tx + t4 * 512;
    int byte = idx * 16;
    int wrow = byte >> 8;
    int off = byte & 255;
    int swz = off ^ ((wrow & 7) << 4);
    *(f16x8*)((char*)WT + wrow * 256 + swz) = *(const f16x8*)((const char*)Wt + byte);
  }

  // up-front A loads (f16x8 per k0 step)
  const int arow = rbase + cl;
  const bool ok = arow < n;
  const f16* rp = H + (size_t)arow * DD + lg * 8;
  f16x8 af[4];
#pragma unroll
  for (int k0 = 0; k0 < 4; ++k0) {
    f16x8 v = {};
    if (ok) v = *(const f16x8*)(rp + k0 * 32);
    af[k0] = v;
  }
  __syncthreads();

  f32x4 acc[8] = {};
#pragma unroll
  for (int k0 = 0; k0 < 4; ++k0) {
#pragma unroll
    for (int c = 0; c < 8; ++c) {
      int col = c * 16 + cl;
      int kb = k0 * 64 + lg * 16;
      int swz = kb ^ ((col & 7) << 4);
      f16x8 bv = *(const f16x8*)((const char*)WT + col * 256 + swz);
      acc[c] = __builtin_amdgcn_mfma_f32_16x16x32_f16(af[k0], bv, acc[c], 0, 0, 0);
    }
  }

  // epilogue: D row = lg*4 + j, col = c*16 + cl -> sliced addr (c*N+row)*16+cl
#pragma unroll
  for (int c = 0; c < 8; ++c) {
    f32x4 a = acc[c];
#pragma unroll
    for (int j = 0; j < 4; ++j) {
      int row = rbase + lg * 4 + j;
      if (row < n) O[((size_t)c * n + row) * 16 + cl] = (f16)a[j];
    }
  }
}

// ---------------- slice-partitioned gather-accumulate (no LN) ------------------
// grid = 8 slices x BPS node-blocks; slice = blockIdx&7 (XCD round-robin
// heuristic for L2 residency; correctness independent of mapping).
// 8-lane groups, f16x2/lane over the slice's 16 cols; 16 nodes per group.
// Emits S = self + bias + gather-sum, sliced f16 layout.
#define AGG_CHUNK 16
__global__ __launch_bounds__(256) void k_agg(const f16* __restrict__ A,
                                             const unsigned* __restrict__ rowptr,
                                             const unsigned* __restrict__ degE,
                                             const float* __restrict__ dinv,
                                             const unsigned* __restrict__ ep,
                                             const float* __restrict__ bias,
                                             f16* __restrict__ S, int n) {
  const int s = blockIdx.x & 7;
  const int bi = blockIdx.x >> 3;
  const int lane = threadIdx.x & 63;
  const int wid = threadIdx.x >> 6;
  const int gl = lane & 7;
  const int gid = bi * 32 + wid * 8 + (lane >> 3);
  const int rA = gid * AGG_CHUNK;
  const f16* As = A + (size_t)s * n * 16;
  f16* Ss = S + (size_t)s * n * 16;
  const float2 bb = *(const float2*)(bias + s * 16 + gl * 2);

  for (int nn = 0; nn < AGG_CHUNK; ++nn) {
    int r = rA + nn;
    if (r >= n) break;
    unsigned e = rowptr[r];
    const unsigned cnt = degE[r];
    const float di = dinv[r];
    const float ws = di * di;
    f16x2 sv = *(const f16x2*)(As + (size_t)r * 16 + gl * 2);
    float ax0 = fmaf(ws, (float)sv[0], bb.x);
    float ay0 = fmaf(ws, (float)sv[1], bb.y);
    float ax1 = 0.f, ay1 = 0.f, ax2 = 0.f, ay2 = 0.f, ax3 = 0.f, ay3 = 0.f;
    unsigned k = 0;
    for (; k + 4 <= cnt; k += 4, e += 4) {
      unsigned m0 = ep[e], m1 = ep[e + 1], m2 = ep[e + 2], m3 = ep[e + 3];
      f16x2 u0 = *(const f16x2*)(As + (size_t)unpackc(m0) * 16 + gl * 2);
      f16x2 u1 = *(const f16x2*)(As + (size_t)unpackc(m1) * 16 + gl * 2);
      f16x2 u2 = *(const f16x2*)(As + (size_t)unpackc(m2) * 16 + gl * 2);
      f16x2 u3 = *(const f16x2*)(As + (size_t)unpackc(m3) * 16 + gl * 2);
      float w0 = unpackw(m0), w1 = unpackw(m1);
      float w2 = unpackw(m2), w3 = unpackw(m3);
      ax0 = fmaf(w0, (float)u0[0], ax0); ay0 = fmaf(w0, (float)u0[1], ay0);
      ax1 = fmaf(w1, (float)u1[0], ax1); ay1 = fmaf(w1, (float)u1[1], ay1);
      ax2 = fmaf(w2, (float)u2[0], ax2); ay2 = fmaf(w2, (float)u2[1], ay2);
      ax3 = fmaf(w3, (float)u3[0], ax3); ay3 = fmaf(w3, (float)u3[1], ay3);
    }
    for (; k < cnt; ++k, ++e) {
      unsigned m = ep[e];
      f16x2 u = *(const f16x2*)(As + (size_t)unpackc(m) * 16 + gl * 2);
      float w = unpackw(m);
      ax0 = fmaf(w, (float)u[0], ax0);
      ay0 = fmaf(w, (float)u[1], ay0);
    }
    float ox = (ax0 + ax1) + (ax2 + ax3);
    float oy = (ay0 + ay1) + (ay2 + ay3);
    f16x2 o2 = {(f16)ox, (f16)oy};
    *(f16x2*)(Ss + (size_t)r * 16 + gl * 2) = o2;
  }
}

// ---------------- LayerNorm + ReLU: S sliced -> row-major ----------------------
// 2 rows per wave, 32 lanes/row, f16x4 per lane. wfp32: fp32 out (final layer).
__global__ __launch_bounds__(256) void k_ln(const f16* __restrict__ S,
                                            const float* __restrict__ g,
                                            const float* __restrict__ beta,
                                            f16* __restrict__ O16,
                                            float* __restrict__ O32,
                                            int n, int wfp32) {
  const int lane = threadIdx.x & 63;
  const int wid = threadIdx.x >> 6;
  const int li = lane & 31;
  const int r = blockIdx.x * 8 + wid * 2 + (lane >> 5);
  if (r >= n) return;
  // cols li*4..li*4+3 live in slice li>>2 at offset (li&3)*4 f16
  f16x4 sv = *(const f16x4*)(S + ((size_t)(li >> 2) * n + r) * 16 + (li & 3) * 4);
  float ax = (float)sv[0], ay = (float)sv[1], az = (float)sv[2], aw = (float)sv[3];
  float ssum = (ax + ay) + (az + aw);
#pragma unroll
  for (int o = 16; o > 0; o >>= 1) ssum += __shfl_xor(ssum, o);
  float mu = ssum * (1.0f / 128.0f);
  float dx = ax - mu, dy = ay - mu, dz = az - mu, dw = aw - mu;
  float q = (dx * dx + dy * dy) + (dz * dz + dw * dw);
#pragma unroll
  for (int o = 16; o > 0; o >>= 1) q += __shfl_xor(q, o);
  float rstd = rsqrtf(q * (1.0f / 128.0f) + 1e-5f);
  float4 gg = *(const float4*)(g + li * 4);
  float4 be4 = *(const float4*)(beta + li * 4);
  float ox = fmaxf(fmaf(dx * rstd, gg.x, be4.x), 0.f);
  float oy = fmaxf(fmaf(dy * rstd, gg.y, be4.y), 0.f);
  float oz = fmaxf(fmaf(dz * rstd, gg.z, be4.z), 0.f);
  float ow = fmaxf(fmaf(dw * rstd, gg.w, be4.w), 0.f);
  if (wfp32) {
    float4 o4 = {ox, oy, oz, ow};
    *(float4*)(O32 + (size_t)r * DD + li * 4) = o4;
  } else {
    f16x4 o4 = {(f16)ox, (f16)oy, (f16)oz, (f16)ow};
    *(f16x4*)(O16 + (size_t)r * DD + li * 4) = o4;
  }
}

// ---------------- host launcher ----------------
extern "C" void kernel_launch(void* const* d_in, const int* in_sizes, int n_in,
                              void* d_out, int out_size, void* d_ws, size_t ws_size,
                              hipStream_t stream) {
  const float* x    = (const float*)d_in[0];
  const int*   erow = (const int*)d_in[1];
  const int*   ecol = (const int*)d_in[2];
  const float* Wm[3] = {(const float*)d_in[3], (const float*)d_in[7],  (const float*)d_in[11]};
  const float* bs[3] = {(const float*)d_in[4], (const float*)d_in[8],  (const float*)d_in[12]};
  const float* gs[3] = {(const float*)d_in[5], (const float*)d_in[9],  (const float*)d_in[13]};
  const float* be[3] = {(const float*)d_in[6], (const float*)d_in[10], (const float*)d_in[14]};
  const int N = in_sizes[0] / DD;
  const int E = in_sizes[1];

  uint8_t* wp = (uint8_t*)d_ws;
  auto alloc = [&](size_t bytes) {
    uint8_t* p = wp;
    wp += (bytes + 255) & ~(size_t)255;
    return p;
  };
  unsigned*       degE   = (unsigned*)alloc((size_t)N * 4);
  float*          dinv   = (float*)alloc((size_t)N * 4);
  unsigned*       rowptr = (unsigned*)alloc((size_t)N * 4);
  unsigned*       bsum   = (unsigned*)alloc(256 * 4);
  unsigned*       boff   = (unsigned*)alloc(256 * 4);
  unsigned short* rank   = (unsigned short*)alloc((size_t)E * 2);
  unsigned*       ep     = (unsigned*)alloc((size_t)E * 4);
  f16*            A_sl   = (f16*)alloc((size_t)N * DD * 2);  // sliced GEMM out
  f16*            S_sl   = (f16*)alloc((size_t)N * DD * 2);  // sliced agg out
  f16*            Hb16   = (f16*)alloc((size_t)N * DD * 2);  // row-major hidden
  f16*            X16    = (f16*)alloc((size_t)N * DD * 2);
  f16*            Wt[3];
  for (int i = 0; i < 3; ++i) Wt[i] = (f16*)alloc(DD * DD * 2);

  const int nb = (N + 1023) / 1024;

  k_zero<<<(N + 255) / 256, 256, 0, stream>>>(degE, N);
  k_deg_count<<<(E + 255) / 256, 256, 0, stream>>>(erow, degE, rank, E);
  k_scan1<<<nb, 256, 0, stream>>>(degE, rowptr, bsum, dinv, N);
  k_scan2<<<1, 256, 0, stream>>>(bsum, boff, nb);
  k_scan3<<<(N + 255) / 256, 256, 0, stream>>>(rowptr, boff, N);
  k_fill<<<2048, 256, 0, stream>>>(erow, ecol, rank, dinv, rowptr, ep, E, N);
  k_xcast<<<(N * DD / 8 + 255) / 256, 256, 0, stream>>>(x, X16, N * DD / 8);
  k_wt3<<<192, 256, 0, stream>>>(Wm[0], Wm[1], Wm[2], Wt[0], Wt[1], Wt[2]);

  const int gemm_grid = (N + 127) / 128;
  const int groups    = (N + AGG_CHUNK - 1) / AGG_CHUNK;       // 8-lane groups/slice
  const int bps       = (groups + 31) / 32;                    // blocks per slice
  const int agg_grid  = bps * 8;
  const int ln_grid   = (N + 7) / 8;

  auto layer = [&](const f16* hin, int li, int last) {
    k_gemm_mfma<<<gemm_grid, 512, 0, stream>>>(hin, Wt[li], A_sl, N);
    k_agg<<<agg_grid, 256, 0, stream>>>(A_sl, rowptr, degE, dinv, ep, bs[li], S_sl, N);
    k_ln<<<ln_grid, 256, 0, stream>>>(S_sl, gs[li], be[li], Hb16, (float*)d_out, N, last);
  };

  layer(X16, 0, 0);
  layer(Hb16, 1, 0);
  layer(Hb16, 2, 1);
}

// Round 9
// 528.072 us; speedup vs baseline: 1.3839x; 1.3839x over previous
//
#include <hip/hip_runtime.h>
#include <hip/hip_bf16.h>
#include <stdint.h>

#define DD 128

typedef _Float16 f16;
typedef f16 f16x4 __attribute__((ext_vector_type(4)));
typedef f16 f16x8 __attribute__((ext_vector_type(8)));
typedef float f32x4 __attribute__((ext_vector_type(4)));

// pack col(17b) | sign-less f16 weight (15b, w>0) in one u32
__device__ __forceinline__ unsigned packcw(int c, float w) {
  f16 h = (f16)w;
  unsigned short us;
  __builtin_memcpy(&us, &h, 2);
  return ((unsigned)us << 17) | (unsigned)c;
}
__device__ __forceinline__ float unpackw(unsigned p) {
  unsigned short us = (unsigned short)(p >> 17);
  f16 h;
  __builtin_memcpy(&h, &us, 2);
  return (float)h;
}
__device__ __forceinline__ int unpackc(unsigned p) { return (int)(p & 0x1FFFFu); }

// ---------------- graph-norm precompute ----------------
__global__ __launch_bounds__(256) void k_zero(unsigned* degE, int n) {
  int i = blockIdx.x * 256 + threadIdx.x;
  if (i < n) degE[i] = 0u;
}

// degree count + per-edge rank (old count value) in one atomic.
__global__ __launch_bounds__(256) void k_deg_count(const int* __restrict__ row,
                                                   unsigned* degE,
                                                   unsigned short* __restrict__ rank,
                                                   int E) {
  int e = blockIdx.x * 256 + threadIdx.x;
  if (e < E) rank[e] = (unsigned short)atomicAdd(&degE[row[e]], 1u);
}

// ---------------- exclusive scan of degE -> rowptr (+ fused dinv) --------------
__global__ __launch_bounds__(256) void k_scan1(const unsigned* __restrict__ degE,
                                               unsigned* __restrict__ rowptr,
                                               unsigned* __restrict__ bsum,
                                               float* __restrict__ dinv, int n) {
  __shared__ unsigned sh[256];
  int tid = threadIdx.x;
  int base = blockIdx.x * 1024 + tid * 4;
  unsigned v0 = (base + 0 < n) ? degE[base + 0] : 0u;
  unsigned v1 = (base + 1 < n) ? degE[base + 1] : 0u;
  unsigned v2 = (base + 2 < n) ? degE[base + 2] : 0u;
  unsigned v3 = (base + 3 < n) ? degE[base + 3] : 0u;
  if (base + 0 < n) dinv[base + 0] = rsqrtf((float)(v0 + 1u));
  if (base + 1 < n) dinv[base + 1] = rsqrtf((float)(v1 + 1u));
  if (base + 2 < n) dinv[base + 2] = rsqrtf((float)(v2 + 1u));
  if (base + 3 < n) dinv[base + 3] = rsqrtf((float)(v3 + 1u));
  unsigned p1 = v0, p2 = p1 + v1, p3 = p2 + v2, tot = p3 + v3;
  sh[tid] = tot;
  __syncthreads();
  for (int off = 1; off < 256; off <<= 1) {
    unsigned t = (tid >= off) ? sh[tid - off] : 0u;
    __syncthreads();
    sh[tid] += t;
    __syncthreads();
  }
  unsigned excl = sh[tid] - tot;
  if (base + 0 < n) rowptr[base + 0] = excl;
  if (base + 1 < n) rowptr[base + 1] = excl + p1;
  if (base + 2 < n) rowptr[base + 2] = excl + p2;
  if (base + 3 < n) rowptr[base + 3] = excl + p3;
  if (tid == 255) bsum[blockIdx.x] = sh[255];
}

__global__ __launch_bounds__(256) void k_scan2(const unsigned* __restrict__ bsum,
                                               unsigned* __restrict__ boff, int nb) {
  __shared__ unsigned sh[256];
  int tid = threadIdx.x;
  unsigned x = (tid < nb) ? bsum[tid] : 0u;
  sh[tid] = x;
  __syncthreads();
  for (int off = 1; off < 256; off <<= 1) {
    unsigned t = (tid >= off) ? sh[tid - off] : 0u;
    __syncthreads();
    sh[tid] += t;
    __syncthreads();
  }
  if (tid < nb) boff[tid] = sh[tid] - x;
}

__global__ __launch_bounds__(256) void k_scan3(unsigned* rowptr,
                                               const unsigned* __restrict__ boff, int n) {
  int i = blockIdx.x * 256 + threadIdx.x;
  if (i < n) rowptr[i] += boff[i >> 10];
}

// ---------------- fill CSR, atomic-free (pos = rowptr[r] + rank[e]) ------------
__global__ __launch_bounds__(256) void k_fill(const int* __restrict__ row,
                                              const int* __restrict__ col,
                                              const unsigned short* __restrict__ rank,
                                              const float* __restrict__ dinv,
                                              const unsigned* __restrict__ rowptr,
                                              unsigned* __restrict__ ep,
                                              int E, int N) {
  const int xcd = blockIdx.x & 7;
  const int blk = blockIdx.x >> 3;  // 0..255
  const int r0 = (int)((size_t)N * xcd / 8);
  const int r1 = (int)((size_t)N * (xcd + 1) / 8);
  const int e0 = (int)((size_t)E * blk / 256);
  const int e1 = (int)((size_t)E * (blk + 1) / 256);
  for (int e = e0 + (int)threadIdx.x; e < e1; e += 256) {
    int r = row[e];
    if (r >= r0 && r < r1) {
      int c = col[e];
      float w = dinv[r] * dinv[c];
      ep[rowptr[r] + (unsigned)rank[e]] = packcw(c, w);
    }
  }
}

// ---------------- x fp32 -> f16 (one-time) ----------------
__global__ __launch_bounds__(256) void k_xcast(const float* __restrict__ X,
                                               f16* __restrict__ Y, int nv8) {
  int i = blockIdx.x * 256 + threadIdx.x;
  if (i >= nv8) return;
  f32x4 a = ((const f32x4*)X)[i * 2];
  f32x4 b = ((const f32x4*)X)[i * 2 + 1];
  f16x8 o;
#pragma unroll
  for (int j = 0; j < 4; ++j) {
    o[j] = (f16)a[j];
    o[j + 4] = (f16)b[j];
  }
  ((f16x8*)Y)[i] = o;
}

// ---------------- all 3 W -> transposed f16 in one launch ----------------------
__global__ __launch_bounds__(256) void k_wt3(const float* __restrict__ W0,
                                             const float* __restrict__ W1,
                                             const float* __restrict__ W2,
                                             f16* __restrict__ T0,
                                             f16* __restrict__ T1,
                                             f16* __restrict__ T2) {
  int i = blockIdx.x * 256 + threadIdx.x;  // over 3*16384
  int m = i >> 14, j = i & 16383;
  const float* W = (m == 0) ? W0 : (m == 1) ? W1 : W2;
  f16* T = (m == 0) ? T0 : (m == 1) ? T1 : T2;
  int k = j >> 7, c = j & 127;
  T[c * 128 + k] = (f16)W[j];
}

// ---------------- GEMM: A16[n,128] = H16[n,128] @ W[128,128], f16 MFMA ---------
// 256 threads = 4 waves, BM=64 (16 rows/wave). 32 KB swizzled W in LDS;
// __launch_bounds__(256,5) -> 5 blocks/CU (LDS 5x32=160 KB) for latency hiding.
__global__ __launch_bounds__(256, 5) void k_gemm_mfma(const f16* __restrict__ H,
                                                      const f16* __restrict__ Wt,
                                                      f16* __restrict__ O, int n) {
  __shared__ short WT[16384];  // 128 cols x 256 B, XOR-swizzled
  const int tx = threadIdx.x;
  const int w = tx >> 6, l = tx & 63;
  const int cl = l & 15, lg = l >> 4;
  const int rbase = blockIdx.x * 64 + w * 16;

  // stage W (2048 16B-units, 8 per thread)
#pragma unroll
  for (int t4 = 0; t4 < 8; ++t4) {
    int idx = tx + t4 * 256;
    int byte = idx * 16;
    int wrow = byte >> 8;
    int off = byte & 255;
    int swz = off ^ ((wrow & 7) << 4);
    *(f16x8*)((char*)WT + wrow * 256 + swz) = *(const f16x8*)((const char*)Wt + byte);
  }

  // up-front A loads (f16x8 per k0 step)
  const int arow = rbase + cl;
  const bool ok = arow < n;
  const f16* rp = H + (size_t)arow * DD + lg * 8;
  f16x8 af[4];
#pragma unroll
  for (int k0 = 0; k0 < 4; ++k0) {
    f16x8 v = {};
    if (ok) v = *(const f16x8*)(rp + k0 * 32);
    af[k0] = v;
  }
  __syncthreads();

  f32x4 acc[8] = {};
#pragma unroll
  for (int k0 = 0; k0 < 4; ++k0) {
#pragma unroll
    for (int c = 0; c < 8; ++c) {
      int col = c * 16 + cl;
      int kb = k0 * 64 + lg * 16;
      int swz = kb ^ ((col & 7) << 4);
      f16x8 bv = *(const f16x8*)((const char*)WT + col * 256 + swz);
      acc[c] = __builtin_amdgcn_mfma_f32_16x16x32_f16(af[k0], bv, acc[c], 0, 0, 0);
    }
  }

  // epilogue: D row = lg*4 + j, col = c*16 + cl  [m89-verified layout]; f16 out
#pragma unroll
  for (int c = 0; c < 8; ++c) {
    int col = c * 16 + cl;
    f32x4 a = acc[c];
#pragma unroll
    for (int j = 0; j < 4; ++j) {
      int row = rbase + lg * 4 + j;
      if (row < n) O[(size_t)row * DD + col] = (f16)a[j];
    }
  }
}

// ---------------- fused: gather-sum + self-loop + bias + LN + ReLU -------------
// 2 nodes per wave (32 lanes x f16x4 each). Packed 4B edge meta. 8-deep edge
// pipeline (8 gathers in flight). f16 hidden out / fp32 final out.
__global__ __launch_bounds__(256) void k_agg_ln(const f16* __restrict__ T,
                                                const unsigned* __restrict__ rowptr,
                                                const unsigned* __restrict__ degE,
                                                const float* __restrict__ dinv,
                                                const unsigned* __restrict__ ep,
                                                const float* __restrict__ bias,
                                                const float* __restrict__ g,
                                                const float* __restrict__ beta,
                                                f16* __restrict__ O16,
                                                float* __restrict__ O32,
                                                int n, int wfp32) {
  const int lane = threadIdx.x & 63;
  const int wid = threadIdx.x >> 6;
  const int li = lane & 31;
  const int r = blockIdx.x * 8 + wid * 2 + (lane >> 5);
  const bool valid = r < n;
  const int rs = valid ? r : (n - 1);

  const unsigned cnt = valid ? degE[rs] : 0u;
  const float di = dinv[rs];
  unsigned e = rowptr[rs];

  unsigned cntO = (unsigned)__shfl_xor((int)cnt, 32);
  int cmw = __builtin_amdgcn_readfirstlane((int)(cnt < cntO ? cnt : cntO));

  const f16* Tl = T + li * 4;
  f16x4 sv = *(const f16x4*)(Tl + (size_t)rs * DD);
  float4 bb = *(const float4*)(bias + li * 4);
  const float ws = di * di;
  float4 a0, a1, a2, a3;
  a0.x = fmaf(ws, (float)sv[0], bb.x);
  a0.y = fmaf(ws, (float)sv[1], bb.y);
  a0.z = fmaf(ws, (float)sv[2], bb.z);
  a0.w = fmaf(ws, (float)sv[3], bb.w);
  a1 = make_float4(0.f, 0.f, 0.f, 0.f);
  a2 = a1; a3 = a1;

  int k = 0;
  unsigned m0, m1, m2, m3, m4, m5, m6, m7;
  if (cmw >= 8) {
    m0 = ep[e + 0]; m1 = ep[e + 1]; m2 = ep[e + 2]; m3 = ep[e + 3];
    m4 = ep[e + 4]; m5 = ep[e + 5]; m6 = ep[e + 6]; m7 = ep[e + 7];
  }
  while (k + 8 <= cmw) {
    unsigned q0, q1, q2, q3, q4, q5, q6, q7;
    if (k + 16 <= cmw) {
      q0 = ep[e + 8];  q1 = ep[e + 9];  q2 = ep[e + 10]; q3 = ep[e + 11];
      q4 = ep[e + 12]; q5 = ep[e + 13]; q6 = ep[e + 14]; q7 = ep[e + 15];
    }
    f16x4 u0 = *(const f16x4*)(Tl + (size_t)unpackc(m0) * DD);
    f16x4 u1 = *(const f16x4*)(Tl + (size_t)unpackc(m1) * DD);
    f16x4 u2 = *(const f16x4*)(Tl + (size_t)unpackc(m2) * DD);
    f16x4 u3 = *(const f16x4*)(Tl + (size_t)unpackc(m3) * DD);
    f16x4 u4 = *(const f16x4*)(Tl + (size_t)unpackc(m4) * DD);
    f16x4 u5 = *(const f16x4*)(Tl + (size_t)unpackc(m5) * DD);
    f16x4 u6 = *(const f16x4*)(Tl + (size_t)unpackc(m6) * DD);
    f16x4 u7 = *(const f16x4*)(Tl + (size_t)unpackc(m7) * DD);
    float w0 = unpackw(m0), w1 = unpackw(m1), w2 = unpackw(m2), w3 = unpackw(m3);
    float w4 = unpackw(m4), w5 = unpackw(m5), w6 = unpackw(m6), w7 = unpackw(m7);
    a0.x = fmaf(w0, (float)u0[0], a0.x); a0.y = fmaf(w0, (float)u0[1], a0.y);
    a0.z = fmaf(w0, (float)u0[2], a0.z); a0.w = fmaf(w0, (float)u0[3], a0.w);
    a1.x = fmaf(w1, (float)u1[0], a1.x); a1.y = fmaf(w1, (float)u1[1], a1.y);
    a1.z = fmaf(w1, (float)u1[2], a1.z); a1.w = fmaf(w1, (float)u1[3], a1.w);
    a2.x = fmaf(w2, (float)u2[0], a2.x); a2.y = fmaf(w2, (float)u2[1], a2.y);
    a2.z = fmaf(w2, (float)u2[2], a2.z); a2.w = fmaf(w2, (float)u2[3], a2.w);
    a3.x = fmaf(w3, (float)u3[0], a3.x); a3.y = fmaf(w3, (float)u3[1], a3.y);
    a3.z = fmaf(w3, (float)u3[2], a3.z); a3.w = fmaf(w3, (float)u3[3], a3.w);
    a0.x = fmaf(w4, (float)u4[0], a0.x); a0.y = fmaf(w4, (float)u4[1], a0.y);
    a0.z = fmaf(w4, (float)u4[2], a0.z); a0.w = fmaf(w4, (float)u4[3], a0.w);
    a1.x = fmaf(w5, (float)u5[0], a1.x); a1.y = fmaf(w5, (float)u5[1], a1.y);
    a1.z = fmaf(w5, (float)u5[2], a1.z); a1.w = fmaf(w5, (float)u5[3], a1.w);
    a2.x = fmaf(w6, (float)u6[0], a2.x); a2.y = fmaf(w6, (float)u6[1], a2.y);
    a2.z = fmaf(w6, (float)u6[2], a2.z); a2.w = fmaf(w6, (float)u6[3], a2.w);
    a3.x = fmaf(w7, (float)u7[0], a3.x); a3.y = fmaf(w7, (float)u7[1], a3.y);
    a3.z = fmaf(w7, (float)u7[2], a3.z); a3.w = fmaf(w7, (float)u7[3], a3.w);
    m0 = q0; m1 = q1; m2 = q2; m3 = q3;
    m4 = q4; m5 = q5; m6 = q6; m7 = q7;
    e += 8;
    k += 8;
  }
  for (; k + 4 <= cmw; k += 4, e += 4) {
    unsigned d0 = ep[e], d1 = ep[e + 1], d2 = ep[e + 2], d3 = ep[e + 3];
    f16x4 u0 = *(const f16x4*)(Tl + (size_t)unpackc(d0) * DD);
    f16x4 u1 = *(const f16x4*)(Tl + (size_t)unpackc(d1) * DD);
    f16x4 u2 = *(const f16x4*)(Tl + (size_t)unpackc(d2) * DD);
    f16x4 u3 = *(const f16x4*)(Tl + (size_t)unpackc(d3) * DD);
    float w0 = unpackw(d0), w1 = unpackw(d1), w2 = unpackw(d2), w3 = unpackw(d3);
    a0.x = fmaf(w0, (float)u0[0], a0.x); a0.y = fmaf(w0, (float)u0[1], a0.y);
    a0.z = fmaf(w0, (float)u0[2], a0.z); a0.w = fmaf(w0, (float)u0[3], a0.w);
    a1.x = fmaf(w1, (float)u1[0], a1.x); a1.y = fmaf(w1, (float)u1[1], a1.y);
    a1.z = fmaf(w1, (float)u1[2], a1.z); a1.w = fmaf(w1, (float)u1[3], a1.w);
    a2.x = fmaf(w2, (float)u2[0], a2.x); a2.y = fmaf(w2, (float)u2[1], a2.y);
    a2.z = fmaf(w2, (float)u2[2], a2.z); a2.w = fmaf(w2, (float)u2[3], a2.w);
    a3.x = fmaf(w3, (float)u3[0], a3.x); a3.y = fmaf(w3, (float)u3[1], a3.y);
    a3.z = fmaf(w3, (float)u3[2], a3.z); a3.w = fmaf(w3, (float)u3[3], a3.w);
  }
  // divergent per-half tail
  for (unsigned kk = (unsigned)k; kk < cnt; ++kk, ++e) {
    unsigned m = ep[e];
    f16x4 u = *(const f16x4*)(Tl + (size_t)unpackc(m) * DD);
    float w = unpackw(m);
    a0.x = fmaf(w, (float)u[0], a0.x); a0.y = fmaf(w, (float)u[1], a0.y);
    a0.z = fmaf(w, (float)u[2], a0.z); a0.w = fmaf(w, (float)u[3], a0.w);
  }
  float4 a;
  a.x = (a0.x + a1.x) + (a2.x + a3.x);
  a.y = (a0.y + a1.y) + (a2.y + a3.y);
  a.z = (a0.z + a1.z) + (a2.z + a3.z);
  a.w = (a0.w + a1.w) + (a2.w + a3.w);

  // LayerNorm within the 32-lane half (128 elems = 4/lane)
  float s = (a.x + a.y) + (a.z + a.w);
#pragma unroll
  for (int o = 16; o > 0; o >>= 1) s += __shfl_xor(s, o);
  float mu = s * (1.0f / 128.0f);
  float dx = a.x - mu, dy = a.y - mu, dz = a.z - mu, dw = a.w - mu;
  float q = (dx * dx + dy * dy) + (dz * dz + dw * dw);
#pragma unroll
  for (int o = 16; o > 0; o >>= 1) q += __shfl_xor(q, o);
  float rstd = rsqrtf(q * (1.0f / 128.0f) + 1e-5f);
  float4 gg = *(const float4*)(g + li * 4);
  float4 be4 = *(const float4*)(beta + li * 4);
  float ox = fmaxf(fmaf(dx * rstd, gg.x, be4.x), 0.f);
  float oy = fmaxf(fmaf(dy * rstd, gg.y, be4.y), 0.f);
  float oz = fmaxf(fmaf(dz * rstd, gg.z, be4.z), 0.f);
  float ow = fmaxf(fmaf(dw * rstd, gg.w, be4.w), 0.f);
  if (valid) {
    if (wfp32) {
      float4 o4 = {ox, oy, oz, ow};
      *(float4*)(O32 + (size_t)r * DD + li * 4) = o4;
    } else {
      f16x4 o4 = {(f16)ox, (f16)oy, (f16)oz, (f16)ow};
      *(f16x4*)(O16 + (size_t)r * DD + li * 4) = o4;
    }
  }
}

// ---------------- host launcher ----------------
extern "C" void kernel_launch(void* const* d_in, const int* in_sizes, int n_in,
                              void* d_out, int out_size, void* d_ws, size_t ws_size,
                              hipStream_t stream) {
  const float* x    = (const float*)d_in[0];
  const int*   erow = (const int*)d_in[1];
  const int*   ecol = (const int*)d_in[2];
  const float* Wm[3] = {(const float*)d_in[3], (const float*)d_in[7],  (const float*)d_in[11]};
  const float* bs[3] = {(const float*)d_in[4], (const float*)d_in[8],  (const float*)d_in[12]};
  const float* gs[3] = {(const float*)d_in[5], (const float*)d_in[9],  (const float*)d_in[13]};
  const float* be[3] = {(const float*)d_in[6], (const float*)d_in[10], (const float*)d_in[14]};
  const int N = in_sizes[0] / DD;
  const int E = in_sizes[1];

  uint8_t* wp = (uint8_t*)d_ws;
  auto alloc = [&](size_t bytes) {
    uint8_t* p = wp;
    wp += (bytes + 255) & ~(size_t)255;
    return p;
  };
  unsigned*       degE   = (unsigned*)alloc((size_t)N * 4);
  float*          dinv   = (float*)alloc((size_t)N * 4);
  unsigned*       rowptr = (unsigned*)alloc((size_t)N * 4);
  unsigned*       bsum   = (unsigned*)alloc(256 * 4);
  unsigned*       boff   = (unsigned*)alloc(256 * 4);
  unsigned short* rank   = (unsigned short*)alloc((size_t)E * 2);
  unsigned*       ep     = (unsigned*)alloc((size_t)E * 4);
  f16*            A16    = (f16*)alloc((size_t)N * DD * 2);
  f16*            Hb16   = (f16*)alloc((size_t)N * DD * 2);
  f16*            X16    = (f16*)alloc((size_t)N * DD * 2);
  f16*            Wt[3];
  for (int i = 0; i < 3; ++i) Wt[i] = (f16*)alloc(DD * DD * 2);

  const int nb = (N + 1023) / 1024;

  k_zero<<<(N + 255) / 256, 256, 0, stream>>>(degE, N);
  k_deg_count<<<(E + 255) / 256, 256, 0, stream>>>(erow, degE, rank, E);
  k_scan1<<<nb, 256, 0, stream>>>(degE, rowptr, bsum, dinv, N);
  k_scan2<<<1, 256, 0, stream>>>(bsum, boff, nb);
  k_scan3<<<(N + 255) / 256, 256, 0, stream>>>(rowptr, boff, N);
  k_fill<<<2048, 256, 0, stream>>>(erow, ecol, rank, dinv, rowptr, ep, E, N);
  k_xcast<<<(N * DD / 8 + 255) / 256, 256, 0, stream>>>(x, X16, N * DD / 8);
  k_wt3<<<192, 256, 0, stream>>>(Wm[0], Wm[1], Wm[2], Wt[0], Wt[1], Wt[2]);

  const int gemm_grid = (N + 63) / 64;
  const int agg_grid  = (N + 7) / 8;

  auto layer = [&](const f16* hin, int li, int last) {
    k_gemm_mfma<<<gemm_grid, 256, 0, stream>>>(hin, Wt[li], A16, N);
    k_agg_ln<<<agg_grid, 256, 0, stream>>>(A16, rowptr, degE, dinv, ep,
                                           bs[li], gs[li], be[li],
                                           Hb16, (float*)d_out, N, last);
  };

  layer(X16, 0, 0);
  layer(Hb16, 1, 0);
  layer(Hb16, 2, 1);
}

// Round 10
// 501.503 us; speedup vs baseline: 1.4572x; 1.0530x over previous
//
#include <hip/hip_runtime.h>
#include <hip/hip_bf16.h>
#include <stdint.h>

#define DD 128

typedef _Float16 f16;
typedef f16 f16x4 __attribute__((ext_vector_type(4)));
typedef f16 f16x8 __attribute__((ext_vector_type(8)));
typedef float f32x4 __attribute__((ext_vector_type(4)));

// pack col(17b) | sign-less f16 weight (15b, w>0) in one u32
__device__ __forceinline__ unsigned packcw(int c, float w) {
  f16 h = (f16)w;
  unsigned short us;
  __builtin_memcpy(&us, &h, 2);
  return ((unsigned)us << 17) | (unsigned)c;
}
__device__ __forceinline__ float unpackw(unsigned p) {
  unsigned short us = (unsigned short)(p >> 17);
  f16 h;
  __builtin_memcpy(&h, &us, 2);
  return (float)h;
}
__device__ __forceinline__ int unpackc(unsigned p) { return (int)(p & 0x1FFFFu); }

// ---------------- graph-norm precompute ----------------
__global__ __launch_bounds__(256) void k_zero(unsigned* degE, int n) {
  int i = blockIdx.x * 256 + threadIdx.x;
  if (i < n) degE[i] = 0u;
}

// degree count + per-edge rank (old count value) in one atomic.
__global__ __launch_bounds__(256) void k_deg_count(const int* __restrict__ row,
                                                   unsigned* degE,
                                                   unsigned short* __restrict__ rank,
                                                   int E) {
  int e = blockIdx.x * 256 + threadIdx.x;
  if (e < E) rank[e] = (unsigned short)atomicAdd(&degE[row[e]], 1u);
}

// ---------------- exclusive scan of degE -> rowptr (+ fused dinv) --------------
__global__ __launch_bounds__(256) void k_scan1(const unsigned* __restrict__ degE,
                                               unsigned* __restrict__ rowptr,
                                               unsigned* __restrict__ bsum,
                                               float* __restrict__ dinv, int n) {
  __shared__ unsigned sh[256];
  int tid = threadIdx.x;
  int base = blockIdx.x * 1024 + tid * 4;
  unsigned v0 = (base + 0 < n) ? degE[base + 0] : 0u;
  unsigned v1 = (base + 1 < n) ? degE[base + 1] : 0u;
  unsigned v2 = (base + 2 < n) ? degE[base + 2] : 0u;
  unsigned v3 = (base + 3 < n) ? degE[base + 3] : 0u;
  if (base + 0 < n) dinv[base + 0] = rsqrtf((float)(v0 + 1u));
  if (base + 1 < n) dinv[base + 1] = rsqrtf((float)(v1 + 1u));
  if (base + 2 < n) dinv[base + 2] = rsqrtf((float)(v2 + 1u));
  if (base + 3 < n) dinv[base + 3] = rsqrtf((float)(v3 + 1u));
  unsigned p1 = v0, p2 = p1 + v1, p3 = p2 + v2, tot = p3 + v3;
  sh[tid] = tot;
  __syncthreads();
  for (int off = 1; off < 256; off <<= 1) {
    unsigned t = (tid >= off) ? sh[tid - off] : 0u;
    __syncthreads();
    sh[tid] += t;
    __syncthreads();
  }
  unsigned excl = sh[tid] - tot;
  if (base + 0 < n) rowptr[base + 0] = excl;
  if (base + 1 < n) rowptr[base + 1] = excl + p1;
  if (base + 2 < n) rowptr[base + 2] = excl + p2;
  if (base + 3 < n) rowptr[base + 3] = excl + p3;
  if (tid == 255) bsum[blockIdx.x] = sh[255];
}

__global__ __launch_bounds__(256) void k_scan2(const unsigned* __restrict__ bsum,
                                               unsigned* __restrict__ boff, int nb) {
  __shared__ unsigned sh[256];
  int tid = threadIdx.x;
  unsigned x = (tid < nb) ? bsum[tid] : 0u;
  sh[tid] = x;
  __syncthreads();
  for (int off = 1; off < 256; off <<= 1) {
    unsigned t = (tid >= off) ? sh[tid - off] : 0u;
    __syncthreads();
    sh[tid] += t;
    __syncthreads();
  }
  if (tid < nb) boff[tid] = sh[tid] - x;
}

__global__ __launch_bounds__(256) void k_scan3(unsigned* rowptr,
                                               const unsigned* __restrict__ boff, int n) {
  int i = blockIdx.x * 256 + threadIdx.x;
  if (i < n) rowptr[i] += boff[i >> 10];
}

// ---------------- fill CSR, atomic-free (pos = rowptr[r] + rank[e]) ------------
__global__ __launch_bounds__(256) void k_fill(const int* __restrict__ row,
                                              const int* __restrict__ col,
                                              const unsigned short* __restrict__ rank,
                                              const float* __restrict__ dinv,
                                              const unsigned* __restrict__ rowptr,
                                              unsigned* __restrict__ ep,
                                              int E, int N) {
  const int xcd = blockIdx.x & 7;
  const int blk = blockIdx.x >> 3;  // 0..255
  const int r0 = (int)((size_t)N * xcd / 8);
  const int r1 = (int)((size_t)N * (xcd + 1) / 8);
  const int e0 = (int)((size_t)E * blk / 256);
  const int e1 = (int)((size_t)E * (blk + 1) / 256);
  for (int e = e0 + (int)threadIdx.x; e < e1; e += 256) {
    int r = row[e];
    if (r >= r0 && r < r1) {
      int c = col[e];
      float w = dinv[r] * dinv[c];
      ep[rowptr[r] + (unsigned)rank[e]] = packcw(c, w);
    }
  }
}

// ---------------- x fp32 -> f16 (one-time) ----------------
__global__ __launch_bounds__(256) void k_xcast(const float* __restrict__ X,
                                               f16* __restrict__ Y, int nv8) {
  int i = blockIdx.x * 256 + threadIdx.x;
  if (i >= nv8) return;
  f32x4 a = ((const f32x4*)X)[i * 2];
  f32x4 b = ((const f32x4*)X)[i * 2 + 1];
  f16x8 o;
#pragma unroll
  for (int j = 0; j < 4; ++j) {
    o[j] = (f16)a[j];
    o[j + 4] = (f16)b[j];
  }
  ((f16x8*)Y)[i] = o;
}

// ---------------- all 3 W -> transposed f16 in one launch ----------------------
__global__ __launch_bounds__(256) void k_wt3(const float* __restrict__ W0,
                                             const float* __restrict__ W1,
                                             const float* __restrict__ W2,
                                             f16* __restrict__ T0,
                                             f16* __restrict__ T1,
                                             f16* __restrict__ T2) {
  int i = blockIdx.x * 256 + threadIdx.x;  // over 3*16384
  int m = i >> 14, j = i & 16383;
  const float* W = (m == 0) ? W0 : (m == 1) ? W1 : W2;
  f16* T = (m == 0) ? T0 : (m == 1) ? T1 : T2;
  int k = j >> 7, c = j & 127;
  T[c * 128 + k] = (f16)W[j];
}

// ---------------- GEMM: A16[n,128] = H16[n,128] @ W[128,128], f16 MFMA ---------
// 256 threads = 4 waves, BM=64 (16 rows/wave). 32 KB swizzled W in LDS.
// SWAPPED-OPERAND mfma(bv, af): D[m][n] = O[rbase+n][c*16+m], so each lane holds
// 4 CONSECUTIVE cols of its OWN row -> f16x4 (8 B) packed stores, 8 per thread
// (vs 32 scalar 2 B stores with the unswapped layout).
__global__ __launch_bounds__(256, 4) void k_gemm_mfma(const f16* __restrict__ H,
                                                      const f16* __restrict__ Wt,
                                                      f16* __restrict__ O, int n) {
  __shared__ short WT[16384];  // 128 cols x 256 B, XOR-swizzled
  const int tx = threadIdx.x;
  const int w = tx >> 6, l = tx & 63;
  const int cl = l & 15, lg = l >> 4;
  const int rbase = blockIdx.x * 64 + w * 16;

  // stage W (2048 16B-units, 8 per thread)
#pragma unroll
  for (int t4 = 0; t4 < 8; ++t4) {
    int idx = tx + t4 * 256;
    int byte = idx * 16;
    int wrow = byte >> 8;
    int off = byte & 255;
    int swz = off ^ ((wrow & 7) << 4);
    *(f16x8*)((char*)WT + wrow * 256 + swz) = *(const f16x8*)((const char*)Wt + byte);
  }

  // up-front A loads (f16x8 per k0 step); lane's row = rbase + cl
  const int arow = rbase + cl;
  const bool ok = arow < n;
  const f16* rp = H + (size_t)arow * DD + lg * 8;
  f16x8 af[4];
#pragma unroll
  for (int k0 = 0; k0 < 4; ++k0) {
    f16x8 v = {};
    if (ok) v = *(const f16x8*)(rp + k0 * 32);
    af[k0] = v;
  }
  __syncthreads();

  f32x4 acc[8] = {};
#pragma unroll
  for (int k0 = 0; k0 < 4; ++k0) {
#pragma unroll
    for (int c = 0; c < 8; ++c) {
      int col = c * 16 + cl;
      int kb = k0 * 64 + lg * 16;
      int swz = kb ^ ((col & 7) << 4);
      f16x8 bv = *(const f16x8*)((const char*)WT + col * 256 + swz);
      // swapped operands: A = W^T block, B = H block
      acc[c] = __builtin_amdgcn_mfma_f32_16x16x32_f16(bv, af[k0], acc[c], 0, 0, 0);
    }
  }

  // epilogue: lane (cl,lg) holds O[rbase+cl][c*16+lg*4 + reg], reg=0..3
  if (ok) {
    f16* orow = O + (size_t)arow * DD;
#pragma unroll
    for (int c = 0; c < 8; ++c) {
      f32x4 a = acc[c];
      f16x4 h4 = {(f16)a[0], (f16)a[1], (f16)a[2], (f16)a[3]};
      *(f16x4*)(orow + c * 16 + lg * 4) = h4;
    }
  }
}

// ---------------- fused: gather-sum + self-loop + bias + LN + ReLU -------------
// r7-verified version (75 us): 2 nodes per wave (32 lanes x f16x4 each),
// packed 4 B edge meta, 4-deep pipeline with meta prefetch. 28 VGPR.
__global__ __launch_bounds__(256) void k_agg_ln(const f16* __restrict__ T,
                                                const unsigned* __restrict__ rowptr,
                                                const unsigned* __restrict__ degE,
                                                const float* __restrict__ dinv,
                                                const unsigned* __restrict__ ep,
                                                const float* __restrict__ bias,
                                                const float* __restrict__ g,
                                                const float* __restrict__ beta,
                                                f16* __restrict__ O16,
                                                float* __restrict__ O32,
                                                int n, int wfp32) {
  const int lane = threadIdx.x & 63;
  const int wid = threadIdx.x >> 6;
  const int li = lane & 31;
  const int r = blockIdx.x * 8 + wid * 2 + (lane >> 5);
  const bool valid = r < n;
  const int rs = valid ? r : (n - 1);

  const unsigned cnt = valid ? degE[rs] : 0u;
  const float di = dinv[rs];
  unsigned e = rowptr[rs];

  unsigned cntO = (unsigned)__shfl_xor((int)cnt, 32);
  int cmw = __builtin_amdgcn_readfirstlane((int)(cnt < cntO ? cnt : cntO));

  const f16* Tl = T + li * 4;
  f16x4 sv = *(const f16x4*)(Tl + (size_t)rs * DD);
  float4 bb = *(const float4*)(bias + li * 4);
  const float ws = di * di;
  float4 a0, a1, a2, a3;
  a0.x = fmaf(ws, (float)sv[0], bb.x);
  a0.y = fmaf(ws, (float)sv[1], bb.y);
  a0.z = fmaf(ws, (float)sv[2], bb.z);
  a0.w = fmaf(ws, (float)sv[3], bb.w);
  a1 = make_float4(0.f, 0.f, 0.f, 0.f);
  a2 = a1; a3 = a1;

  int k = 0;
  unsigned m0, m1, m2, m3;
  if (cmw >= 4) { m0 = ep[e]; m1 = ep[e + 1]; m2 = ep[e + 2]; m3 = ep[e + 3]; }
  while (k + 4 <= cmw) {
    unsigned q0, q1, q2, q3;
    if (k + 8 <= cmw) {
      q0 = ep[e + 4]; q1 = ep[e + 5]; q2 = ep[e + 6]; q3 = ep[e + 7];
    }
    f16x4 u0 = *(const f16x4*)(Tl + (size_t)unpackc(m0) * DD);
    f16x4 u1 = *(const f16x4*)(Tl + (size_t)unpackc(m1) * DD);
    f16x4 u2 = *(const f16x4*)(Tl + (size_t)unpackc(m2) * DD);
    f16x4 u3 = *(const f16x4*)(Tl + (size_t)unpackc(m3) * DD);
    float w0 = unpackw(m0), w1 = unpackw(m1);
    float w2 = unpackw(m2), w3 = unpackw(m3);
    a0.x = fmaf(w0, (float)u0[0], a0.x); a0.y = fmaf(w0, (float)u0[1], a0.y);
    a0.z = fmaf(w0, (float)u0[2], a0.z); a0.w = fmaf(w0, (float)u0[3], a0.w);
    a1.x = fmaf(w1, (float)u1[0], a1.x); a1.y = fmaf(w1, (float)u1[1], a1.y);
    a1.z = fmaf(w1, (float)u1[2], a1.z); a1.w = fmaf(w1, (float)u1[3], a1.w);
    a2.x = fmaf(w2, (float)u2[0], a2.x); a2.y = fmaf(w2, (float)u2[1], a2.y);
    a2.z = fmaf(w2, (float)u2[2], a2.z); a2.w = fmaf(w2, (float)u2[3], a2.w);
    a3.x = fmaf(w3, (float)u3[0], a3.x); a3.y = fmaf(w3, (float)u3[1], a3.y);
    a3.z = fmaf(w3, (float)u3[2], a3.z); a3.w = fmaf(w3, (float)u3[3], a3.w);
    m0 = q0; m1 = q1; m2 = q2; m3 = q3;
    e += 4;
    k += 4;
  }
  // divergent per-half tail
  for (unsigned kk = (unsigned)k; kk < cnt; ++kk, ++e) {
    unsigned m = ep[e];
    f16x4 u = *(const f16x4*)(Tl + (size_t)unpackc(m) * DD);
    float w = unpackw(m);
    a0.x = fmaf(w, (float)u[0], a0.x); a0.y = fmaf(w, (float)u[1], a0.y);
    a0.z = fmaf(w, (float)u[2], a0.z); a0.w = fmaf(w, (float)u[3], a0.w);
  }
  float4 a;
  a.x = (a0.x + a1.x) + (a2.x + a3.x);
  a.y = (a0.y + a1.y) + (a2.y + a3.y);
  a.z = (a0.z + a1.z) + (a2.z + a3.z);
  a.w = (a0.w + a1.w) + (a2.w + a3.w);

  // LayerNorm within the 32-lane half (128 elems = 4/lane)
  float s = (a.x + a.y) + (a.z + a.w);
#pragma unroll
  for (int o = 16; o > 0; o >>= 1) s += __shfl_xor(s, o);
  float mu = s * (1.0f / 128.0f);
  float dx = a.x - mu, dy = a.y - mu, dz = a.z - mu, dw = a.w - mu;
  float q = (dx * dx + dy * dy) + (dz * dz + dw * dw);
#pragma unroll
  for (int o = 16; o > 0; o >>= 1) q += __shfl_xor(q, o);
  float rstd = rsqrtf(q * (1.0f / 128.0f) + 1e-5f);
  float4 gg = *(const float4*)(g + li * 4);
  float4 be4 = *(const float4*)(beta + li * 4);
  float ox = fmaxf(fmaf(dx * rstd, gg.x, be4.x), 0.f);
  float oy = fmaxf(fmaf(dy * rstd, gg.y, be4.y), 0.f);
  float oz = fmaxf(fmaf(dz * rstd, gg.z, be4.z), 0.f);
  float ow = fmaxf(fmaf(dw * rstd, gg.w, be4.w), 0.f);
  if (valid) {
    if (wfp32) {
      float4 o4 = {ox, oy, oz, ow};
      *(float4*)(O32 + (size_t)r * DD + li * 4) = o4;
    } else {
      f16x4 o4 = {(f16)ox, (f16)oy, (f16)oz, (f16)ow};
      *(f16x4*)(O16 + (size_t)r * DD + li * 4) = o4;
    }
  }
}

// ---------------- host launcher ----------------
extern "C" void kernel_launch(void* const* d_in, const int* in_sizes, int n_in,
                              void* d_out, int out_size, void* d_ws, size_t ws_size,
                              hipStream_t stream) {
  const float* x    = (const float*)d_in[0];
  const int*   erow = (const int*)d_in[1];
  const int*   ecol = (const int*)d_in[2];
  const float* Wm[3] = {(const float*)d_in[3], (const float*)d_in[7],  (const float*)d_in[11]};
  const float* bs[3] = {(const float*)d_in[4], (const float*)d_in[8],  (const float*)d_in[12]};
  const float* gs[3] = {(const float*)d_in[5], (const float*)d_in[9],  (const float*)d_in[13]};
  const float* be[3] = {(const float*)d_in[6], (const float*)d_in[10], (const float*)d_in[14]};
  const int N = in_sizes[0] / DD;
  const int E = in_sizes[1];

  uint8_t* wp = (uint8_t*)d_ws;
  auto alloc = [&](size_t bytes) {
    uint8_t* p = wp;
    wp += (bytes + 255) & ~(size_t)255;
    return p;
  };
  unsigned*       degE   = (unsigned*)alloc((size_t)N * 4);
  float*          dinv   = (float*)alloc((size_t)N * 4);
  unsigned*       rowptr = (unsigned*)alloc((size_t)N * 4);
  unsigned*       bsum   = (unsigned*)alloc(256 * 4);
  unsigned*       boff   = (unsigned*)alloc(256 * 4);
  unsigned short* rank   = (unsigned short*)alloc((size_t)E * 2);
  unsigned*       ep     = (unsigned*)alloc((size_t)E * 4);
  f16*            A16    = (f16*)alloc((size_t)N * DD * 2);
  f16*            Hb16   = (f16*)alloc((size_t)N * DD * 2);
  f16*            X16    = (f16*)alloc((size_t)N * DD * 2);
  f16*            Wt[3];
  for (int i = 0; i < 3; ++i) Wt[i] = (f16*)alloc(DD * DD * 2);

  const int nb = (N + 1023) / 1024;

  k_zero<<<(N + 255) / 256, 256, 0, stream>>>(degE, N);
  k_deg_count<<<(E + 255) / 256, 256, 0, stream>>>(erow, degE, rank, E);
  k_scan1<<<nb, 256, 0, stream>>>(degE, rowptr, bsum, dinv, N);
  k_scan2<<<1, 256, 0, stream>>>(bsum, boff, nb);
  k_scan3<<<(N + 255) / 256, 256, 0, stream>>>(rowptr, boff, N);
  k_fill<<<2048, 256, 0, stream>>>(erow, ecol, rank, dinv, rowptr, ep, E, N);
  k_xcast<<<(N * DD / 8 + 255) / 256, 256, 0, stream>>>(x, X16, N * DD / 8);
  k_wt3<<<192, 256, 0, stream>>>(Wm[0], Wm[1], Wm[2], Wt[0], Wt[1], Wt[2]);

  const int gemm_grid = (N + 63) / 64;
  const int agg_grid  = (N + 7) / 8;

  auto layer = [&](const f16* hin, int li, int last) {
    k_gemm_mfma<<<gemm_grid, 256, 0, stream>>>(hin, Wt[li], A16, N);
    k_agg_ln<<<agg_grid, 256, 0, stream>>>(A16, rowptr, degE, dinv, ep,
                                           bs[li], gs[li], be[li],
                                           Hb16, (float*)d_out, N, last);
  };

  layer(X16, 0, 0);
  layer(Hb16, 1, 0);
  layer(Hb16, 2, 1);
}